// Round 10
// baseline (234.750 us; speedup 1.0000x reference)
//
#include <hip/hip_runtime.h>
#include <math.h>

// Fused Conv2d(16->64,3x3,VALID)+bias -> min(oc) -> tanh(tanh()).
// R10: same 2-term weight-split math as R9 (y = bf16(x)*wh + bf16(x)*wl),
// restructured as an intra-block 2-phase double-buffer:
//   stage buf0(rows0-9) | barrier | issue loads(rows8-17) -> MFMA rows0-7
//   -> convert+write buf1 | barrier | MFMA rows8-15.
// Breaks the R9 phase-serialization (MFMA 33 + LDS 25 + VALU 22 ~= 87us
// measured serial sum) by overlapping stage-B with compute-A in-block.

#define IN_C  16
#define OUT_C 64
#define HH    256
#define WW    256
#define OHH   254
#define OWW   254
#define NB    32

#define TH 16       // output rows per block
#define PH 8        // output rows per phase
#define TW 32       // output cols per block (= MFMA N)
#define HRP 10      // input rows per buffer (PH + 2 halo)
#define HC 34       // halo cols staged
#define NCP 17      // 64B cells per row (2 cols packed per cell)
#define ROWB (NCP * 64)       // 1088 B per LDS row
#define NITEM (HRP * HC)      // 340 items per phase

typedef __attribute__((ext_vector_type(8)))  short short8;    // 8 bf16
typedef __attribute__((ext_vector_type(16))) float floatx16;  // 16 f32 acc

__device__ __forceinline__ unsigned short f2bf(float f) {   // RNE
    unsigned u = __float_as_uint(f);
    u = u + 0x7FFFu + ((u >> 16) & 1u);
    return (unsigned short)(u >> 16);
}
__device__ __forceinline__ float bf2f(unsigned short h) {
    return __uint_as_float(((unsigned)h) << 16);
}

// LDS cell(r, cp) = 64B = 4 slots of 16B. Logical slot for column colh
// (cp = colh>>1), channel block cblk: s = (colh&1)*2 + cblk. Physical
// slot = s ^ swz2(cp): any 32-consecutive-colh b128 read window is
// conflict-free (proven R8/R9 geometry).
__device__ __forceinline__ int swz2(int cp) {
    return (cp ^ (cp >> 2)) & 3;
}
__device__ __forceinline__ int cell_addr(int r, int colh, int cblk) {
    const int cp = colh >> 1;
    const int s  = ((colh & 1) << 1) + cblk;
    return r * ROWB + cp * 64 + ((s ^ swz2(cp)) << 4);
}

// tanh(tanh(v)) via fast exp; saturates correctly at +-large.
__device__ __forceinline__ float tanh2_fast(float v) {
    const float e1 = __expf(2.0f * v);
    const float t1 = 1.0f - 2.0f / (e1 + 1.0f);
    const float e2 = __expf(2.0f * t1);
    return 1.0f - 2.0f / (e2 + 1.0f);
}

// ---- pre-kernel: split weights/bias to MFMA-fragment order in d_ws ----
__global__ void split_weights(const float* __restrict__ w,
                              const float* __restrict__ bias,
                              short8* __restrict__ ws)
{
    const int tid = threadIdx.x;
    if (tid >= 128) return;
    const int oct  = tid >> 6;
    const int lane = tid & 63;
    const int oc   = oct * 32 + (lane & 31);
    const int cb   = (lane >> 5) * 8;
#pragma unroll
    for (int t = 0; t < 9; ++t) {
        const int kh = t / 3, kw = t % 3;
        short8 hi, lo;
#pragma unroll
        for (int j = 0; j < 8; ++j) {
            const float wv = w[((oc * IN_C + cb + j) * 3 + kh) * 3 + kw];
            const unsigned short h = f2bf(wv);
            hi[j] = (short)h;
            lo[j] = (short)f2bf(wv - bf2f(h));
        }
        ws[(oct * 10 + t) * 64 + lane]        = hi;
        ws[1280 + (oct * 9 + t) * 64 + lane]  = lo;
    }
    short8 wb = {};
    if (lane < 32) {
        const float bv = bias[oc];
        const unsigned short h = f2bf(bv);
        wb[0] = (short)h;
        wb[1] = (short)f2bf(bv - bf2f(h));
    }
    ws[(oct * 10 + 9) * 64 + lane] = wb;
}

__global__ __launch_bounds__(256, 3)
void conv_min_tanh_mfma7(const float* __restrict__ x,
                         const short8* __restrict__ ws,
                         float* __restrict__ out)
{
    __shared__ __align__(64) unsigned char lds0[HRP * ROWB];   // 10880 B
    __shared__ __align__(64) unsigned char lds1[HRP * ROWB];   // 10880 B
    __shared__ float comb[2][TH][TW];                          // 4096 B

    const int tid  = threadIdx.x;
    const int lane = tid & 63;
    const int wave = tid >> 6;

    const int bx      = blockIdx.x;      // 0..127
    const int coltile = bx & 7;
    const int rowtile = bx >> 3;         // 0..15
    const int n       = blockIdx.y;
    const int oh0     = rowtile * TH;
    const int ow0     = coltile * TW;

    const float* xn = x + (size_t)n * IN_C * HH * WW;

    // ---- weight fragments from d_ws (L2-resident, fragment-ordered) ----
    const int oct = wave & 1;            // waves 0,1: oc 0-31 / 32-63
    const int qrw = (wave >> 1) * 4;     // wave row-quad base within phase
    short8 whi[10], wlo[9];
#pragma unroll
    for (int t = 0; t < 10; ++t) whi[t] = ws[(oct * 10 + t) * 64 + lane];
#pragma unroll
    for (int t = 0; t < 9; ++t)  wlo[t] = ws[1280 + (oct * 9 + t) * 64 + lane];
    short8 ones = {};
    if (lane < 32) { ones[0] = (short)0x3F80; ones[1] = (short)0x3F80; }

    // per-thread staging item coords (item i = tid and i+256)
    const int r1 = tid / HC, colh1 = tid - r1 * HC;                    // < 340 always
    const int i2 = tid + 256;
    const int r2 = i2 / HC, colh2 = i2 - r2 * HC;
    const bool has2 = (i2 < NITEM);

    // fragment-read offsets (col-only swizzle, row-invariant)
    const int colb = lane & 31;
    const int cblk = lane >> 5;
    int off2[3];
#pragma unroll
    for (int kw = 0; kw < 3; ++kw)
        off2[kw] = cell_addr(0, colb + kw, cblk);

    // ---- prologue: fully stage buf0 (input rows 0..9) ----
    {
        const float* xp1 = xn + min(oh0 + r1, HH - 1) * WW + min(ow0 + colh1, WW - 1);
        short8 a0, a1;
#pragma unroll
        for (int j = 0; j < 8; ++j) {
            a0[j] = (short)f2bf(xp1[j * (HH * WW)]);
            a1[j] = (short)f2bf(xp1[(j + 8) * (HH * WW)]);
        }
        *(short8*)(lds0 + cell_addr(r1, colh1, 0)) = a0;
        *(short8*)(lds0 + cell_addr(r1, colh1, 1)) = a1;
        if (has2) {
            const float* xp2 = xn + min(oh0 + r2, HH - 1) * WW + min(ow0 + colh2, WW - 1);
            short8 b0, b1;
#pragma unroll
            for (int j = 0; j < 8; ++j) {
                b0[j] = (short)f2bf(xp2[j * (HH * WW)]);
                b1[j] = (short)f2bf(xp2[(j + 8) * (HH * WW)]);
            }
            *(short8*)(lds0 + cell_addr(r2, colh2, 0)) = b0;
            *(short8*)(lds0 + cell_addr(r2, colh2, 1)) = b1;
        }
    }
    __syncthreads();

    // ---- issue phase-B global loads EARLY (input rows 8..17) ----
    float u1[IN_C], u2[IN_C];
    {
        const float* xp1 = xn + min(oh0 + 8 + r1, HH - 1) * WW + min(ow0 + colh1, WW - 1);
#pragma unroll
        for (int c = 0; c < IN_C; ++c) u1[c] = xp1[c * (HH * WW)];
        if (has2) {
            const float* xp2 = xn + min(oh0 + 8 + r2, HH - 1) * WW + min(ow0 + colh2, WW - 1);
#pragma unroll
            for (int c = 0; c < IN_C; ++c) u2[c] = xp2[c * (HH * WW)];
        }
    }

    // ---- MFMA phase A: output rows 0..7 from buf0 ----
#pragma unroll
    for (int rr = 0; rr < 4; ++rr) {
        const int rl = qrw + rr;                 // output row in tile (0..7)
        floatx16 acc = {};
#pragma unroll
        for (int t = 0; t < 9; ++t) {
            const int kh = t / 3, kw = t % 3;
            const short8 bhi = *(const short8*)(lds0 + (rl + kh) * ROWB + off2[kw]);
            acc = __builtin_amdgcn_mfma_f32_32x32x16_bf16(whi[t], bhi, acc, 0, 0, 0);
            acc = __builtin_amdgcn_mfma_f32_32x32x16_bf16(wlo[t], bhi, acc, 0, 0, 0);
        }
        acc = __builtin_amdgcn_mfma_f32_32x32x16_bf16(whi[9], ones, acc, 0, 0, 0);
        float m0 = fminf(acc[0],  acc[1]),  m1 = fminf(acc[2],  acc[3]);
        float m2 = fminf(acc[4],  acc[5]),  m3 = fminf(acc[6],  acc[7]);
        float m4 = fminf(acc[8],  acc[9]),  m5 = fminf(acc[10], acc[11]);
        float m6 = fminf(acc[12], acc[13]), m7 = fminf(acc[14], acc[15]);
        m0 = fminf(m0, m1); m2 = fminf(m2, m3); m4 = fminf(m4, m5); m6 = fminf(m6, m7);
        m0 = fminf(m0, m2); m4 = fminf(m4, m6);
        float mv = fminf(m0, m4);
        mv = fminf(mv, __shfl_xor(mv, 32, 64));
        if (lane < 32) comb[oct][rl][lane] = mv;
    }

    // ---- convert + write buf1 LATE ----
    {
        short8 a0, a1;
#pragma unroll
        for (int j = 0; j < 8; ++j) {
            a0[j] = (short)f2bf(u1[j]);
            a1[j] = (short)f2bf(u1[j + 8]);
        }
        *(short8*)(lds1 + cell_addr(r1, colh1, 0)) = a0;
        *(short8*)(lds1 + cell_addr(r1, colh1, 1)) = a1;
        if (has2) {
            short8 b0, b1;
#pragma unroll
            for (int j = 0; j < 8; ++j) {
                b0[j] = (short)f2bf(u2[j]);
                b1[j] = (short)f2bf(u2[j + 8]);
            }
            *(short8*)(lds1 + cell_addr(r2, colh2, 0)) = b0;
            *(short8*)(lds1 + cell_addr(r2, colh2, 1)) = b1;
        }
    }
    __syncthreads();

    // ---- MFMA phase B: output rows 8..15 from buf1 (local row = rl-8) ----
#pragma unroll
    for (int rr = 0; rr < 4; ++rr) {
        const int rl  = 8 + qrw + rr;            // output row in tile (8..15)
        const int rloc = qrw + rr;               // local input row base in buf1
        floatx16 acc = {};
#pragma unroll
        for (int t = 0; t < 9; ++t) {
            const int kh = t / 3, kw = t % 3;
            const short8 bhi = *(const short8*)(lds1 + (rloc + kh) * ROWB + off2[kw]);
            acc = __builtin_amdgcn_mfma_f32_32x32x16_bf16(whi[t], bhi, acc, 0, 0, 0);
            acc = __builtin_amdgcn_mfma_f32_32x32x16_bf16(wlo[t], bhi, acc, 0, 0, 0);
        }
        acc = __builtin_amdgcn_mfma_f32_32x32x16_bf16(whi[9], ones, acc, 0, 0, 0);
        float m0 = fminf(acc[0],  acc[1]),  m1 = fminf(acc[2],  acc[3]);
        float m2 = fminf(acc[4],  acc[5]),  m3 = fminf(acc[6],  acc[7]);
        float m4 = fminf(acc[8],  acc[9]),  m5 = fminf(acc[10], acc[11]);
        float m6 = fminf(acc[12], acc[13]), m7 = fminf(acc[14], acc[15]);
        m0 = fminf(m0, m1); m2 = fminf(m2, m3); m4 = fminf(m4, m5); m6 = fminf(m6, m7);
        m0 = fminf(m0, m2); m4 = fminf(m4, m6);
        float mv = fminf(m0, m4);
        mv = fminf(mv, __shfl_xor(mv, 32, 64));
        if (lane < 32) comb[oct][rl][lane] = mv;
    }

    __syncthreads();

    // ---- combine oc-tiles, tanh(tanh()), masked store ----
    for (int i = tid; i < TH * TW; i += 256) {
        const int row  = i >> 5;
        const int colp = i & 31;
        const int oh = oh0 + row;
        const int ow = ow0 + colp;
        if (oh < OHH && ow < OWW) {
            out[((size_t)n * OHH + oh) * OWW + ow] =
                tanh2_fast(fminf(comb[0][row][colp], comb[1][row][colp]));
        }
    }
}

extern "C" void kernel_launch(void* const* d_in, const int* in_sizes, int n_in,
                              void* d_out, int out_size, void* d_ws, size_t ws_size,
                              hipStream_t stream)
{
    const float* x = (const float*)d_in[0];
    const float* w = (const float*)d_in[1];
    const float* b = (const float*)d_in[2];
    float* out     = (float*)d_out;
    short8* ws     = (short8*)d_ws;   // 38912 B used

    split_weights<<<1, 128, 0, stream>>>(w, b, ws);
    dim3 grid(16 * 8, NB);   // 16 row-tiles * 8 col-tiles, 32 batches
    conv_min_tanh_mfma7<<<grid, 256, 0, stream>>>(x, ws, out);
}